// Round 1
// baseline (103.376 us; speedup 1.0000x reference)
//
#include <hip/hip_runtime.h>
#include <math.h>

// DynOT: 200-iteration log-domain Sinkhorn on a 64x6 kernel matrix.
// One wave (64 lanes), lane i = row i. Everything in registers.
// Column reductions via DPP (row_shr + row_bcast), no LDS, no barriers.

constexpr int L = 64;
constexpr int B = 6;
constexpr int ITERS = 200;
constexpr float INV_EPS = 50.0f; // 1 / 0.02

// One butterfly-style reduction step: v += dpp_shuffle(v), invalid lanes read 0.
template <int CTRL>
__device__ __forceinline__ float dpp_add(float v) {
    int x = __builtin_bit_cast(int, v);
    int y = __builtin_amdgcn_update_dpp(0, x, CTRL, 0xF, 0xF, true);
    return v + __builtin_bit_cast(float, y);
}

// Full 64-lane sum, result broadcast to all lanes via readlane (SGPR).
// Chain: row_shr 1,2,4,8 (intra-16 prefix) -> lane15/31/47/63 hold row sums;
// row_bcast15 -> lane31 = rows0+1, lane63 = rows2+3; row_bcast31 -> lane63 = all.
__device__ __forceinline__ float wave_sum64(float v) {
    v = dpp_add<0x111>(v); // row_shr:1
    v = dpp_add<0x112>(v); // row_shr:2
    v = dpp_add<0x114>(v); // row_shr:4
    v = dpp_add<0x118>(v); // row_shr:8
    v = dpp_add<0x142>(v); // row_bcast:15
    v = dpp_add<0x143>(v); // row_bcast:31
    int t = __builtin_amdgcn_readlane(__builtin_bit_cast(int, v), 63);
    return __builtin_bit_cast(float, t);
}

__global__ __launch_bounds__(64) void dynot_sinkhorn_kernel(
    const float* __restrict__ trH, const float* __restrict__ wmax,
    const float* __restrict__ a, const float* __restrict__ theta,
    const float* __restrict__ phi, const int* __restrict__ bits,
    float* __restrict__ out)
{
    const int i = threadIdx.x; // row index, one wave of 64

    const float trH_i = trH[i];
    const float wmax_i = wmax[i];
    const float a_i = a[i];

    // b = softmax(phi), log-domain; computed redundantly per lane (uniform).
    float ph[B];
#pragma unroll
    for (int j = 0; j < B; ++j) ph[j] = phi[j];
    float mp = ph[0];
#pragma unroll
    for (int j = 1; j < B; ++j) mp = fmaxf(mp, ph[j]);
    float eb[B];
    float sb = 0.0f;
#pragma unroll
    for (int j = 0; j < B; ++j) { eb[j] = expf(ph[j] - mp); sb += eb[j]; }
    float lnb[B];
#pragma unroll
    for (int j = 0; j < B; ++j) lnb[j] = logf(eb[j] / sb + 1e-40f);

    const float lna = logf(a_i + 1e-40f);

    // K[i][j] = -(C - theta)/eps ; C = 0.5*trH*(delta^2/12) = trH*delta^2/24
    float K[B];
#pragma unroll
    for (int j = 0; j < B; ++j) {
        float denom = (float)((1 << bits[j]) - 1); // 2^b - 1, exact
        float delta = 2.0f * wmax_i / denom;
        float C = trH_i * delta * delta * (1.0f / 24.0f);
        K[j] = (theta[i * B + j] - C) * INV_EPS;
    }

    float f = 0.0f;
    float g[B];
#pragma unroll
    for (int j = 0; j < B; ++j) g[j] = 0.0f;

#pragma unroll 1
    for (int it = 0; it < ITERS; ++it) {
        // f = log a - logsumexp_j(K + g)   (in-lane, 6 elements, max-subtracted)
        float t[B];
#pragma unroll
        for (int j = 0; j < B; ++j) t[j] = K[j] + g[j];
        float mx = fmaxf(fmaxf(fmaxf(t[0], t[1]), fmaxf(t[2], t[3])), fmaxf(t[4], t[5]));
        float s = 0.0f;
#pragma unroll
        for (int j = 0; j < B; ++j) s += __expf(t[j] - mx);
        f = lna - (mx + __logf(s));

        // g[j] = log b[j] - log( sum_i exp(K[i][j] + f[i]) )
        // No max-subtraction: input ranges bound exponents well inside f32
        // (|K| <= ~40 ln-domain, sum_j <= e^{-g_j} * sum a = e^{-g_j}).
        float S[B];
#pragma unroll
        for (int j = 0; j < B; ++j) S[j] = wave_sum64(__expf(K[j] + f));
#pragma unroll
        for (int j = 0; j < B; ++j) g[j] = lnb[j] - __logf(S[j]);
    }

    // P = exp(K + f + g); normalize by global sum.
    float p[B];
    float loc = 0.0f;
#pragma unroll
    for (int j = 0; j < B; ++j) { p[j] = __expf(K[j] + f + g[j]); loc += p[j]; }
    float tot = wave_sum64(loc) + 1e-40f;
    float inv = 1.0f / tot;
#pragma unroll
    for (int j = 0; j < B; ++j) out[i * B + j] = p[j] * inv;
}

extern "C" void kernel_launch(void* const* d_in, const int* in_sizes, int n_in,
                              void* d_out, int out_size, void* d_ws, size_t ws_size,
                              hipStream_t stream) {
    const float* trH   = (const float*)d_in[0];
    const float* wmaxp = (const float*)d_in[1];
    const float* a     = (const float*)d_in[2];
    const float* theta = (const float*)d_in[3];
    const float* phi   = (const float*)d_in[4];
    const int*   bits  = (const int*)d_in[5];
    float* out = (float*)d_out;

    hipLaunchKernelGGL(dynot_sinkhorn_kernel, dim3(1), dim3(64), 0, stream,
                       trH, wmaxp, a, theta, phi, bits, out);
}

// Round 2
// 63.051 us; speedup vs baseline: 1.6396x; 1.6396x over previous
//
#include <hip/hip_runtime.h>
#include <math.h>

// DynOT: 200-iter Sinkhorn on 64x6, reformulated in LINEAR domain:
//   v = a ./ (M u),  u = b ./ (M^T v),  M = exp((theta - C)/eps)
// One wave, lane i = row i. Column sums via all-lane DPP butterfly
// (quad_perm/mirror + gfx950 v_permlane16/32_swap). No exp/log in the loop.

constexpr int B = 6;
constexpr int ITERS = 200;
constexpr float INV_EPS = 50.0f; // 1 / 0.02

typedef float v2f __attribute__((ext_vector_type(2)));

template <int CTRL>
__device__ __forceinline__ float dpp_mov(float v) {
    return __builtin_bit_cast(float,
        __builtin_amdgcn_update_dpp(0, __builtin_bit_cast(int, v), CTRL, 0xF, 0xF, true));
}

// One butterfly step on a packed pair: x += shuffle(x). CTRL values:
// 0xB1 quad_perm[1,0,3,2] (xor1), 0x4E quad_perm[2,3,0,1] (xor2),
// 0x141 row_half_mirror (pairs quads within 8), 0x140 row_mirror (within 16).
template <int CTRL>
__device__ __forceinline__ v2f bfly_dpp(v2f x) {
    v2f y;
    y.x = dpp_mov<CTRL>(x.x);
    y.y = dpp_mov<CTRL>(x.y);
    return x + y;
}

// xor16 / xor32 exchange via gfx950 permlane swaps; s_nop covers the
// VALU-write -> permlane-read hazard (asm is invisible to the scheduler).
__device__ __forceinline__ v2f bfly_swap16(v2f x) {
    float a0 = x.x, b0 = x.x, a1 = x.y, b1 = x.y;
    asm volatile("s_nop 1\n\t"
                 "v_permlane16_swap_b32 %0, %1\n\t"
                 "v_permlane16_swap_b32 %2, %3"
                 : "+v"(a0), "+v"(b0), "+v"(a1), "+v"(b1));
    v2f s, t;
    s.x = a0; s.y = a1;
    t.x = b0; t.y = b1;
    return s + t;
}
__device__ __forceinline__ v2f bfly_swap32(v2f x) {
    float a0 = x.x, b0 = x.x, a1 = x.y, b1 = x.y;
    asm volatile("s_nop 1\n\t"
                 "v_permlane32_swap_b32 %0, %1\n\t"
                 "v_permlane32_swap_b32 %2, %3"
                 : "+v"(a0), "+v"(b0), "+v"(a1), "+v"(b1));
    v2f s, t;
    s.x = a0; s.y = a1;
    t.x = b0; t.y = b1;
    return s + t;
}

__device__ __forceinline__ float wave_allsum64(float v) {
    v += dpp_mov<0xB1>(v);
    v += dpp_mov<0x4E>(v);
    v += dpp_mov<0x141>(v);
    v += dpp_mov<0x140>(v);
    {
        float a = v, b = v;
        asm volatile("s_nop 1\n\tv_permlane16_swap_b32 %0, %1" : "+v"(a), "+v"(b));
        v = a + b;
    }
    {
        float a = v, b = v;
        asm volatile("s_nop 1\n\tv_permlane32_swap_b32 %0, %1" : "+v"(a), "+v"(b));
        v = a + b;
    }
    return v;
}

__global__ __launch_bounds__(64) void dynot_sinkhorn_kernel(
    const float* __restrict__ trH, const float* __restrict__ wmax,
    const float* __restrict__ a, const float* __restrict__ theta,
    const float* __restrict__ phi, const int* __restrict__ bits,
    float* __restrict__ out)
{
    const int i = threadIdx.x; // row index, one wave of 64

    const float trH_i = trH[i];
    const float wmax_i = wmax[i];
    const float a_i = a[i];

    // b = softmax(phi), linear domain (uniform across lanes)
    float ph[B];
#pragma unroll
    for (int j = 0; j < B; ++j) ph[j] = phi[j];
    float mp = fmaxf(fmaxf(fmaxf(ph[0], ph[1]), fmaxf(ph[2], ph[3])), fmaxf(ph[4], ph[5]));
    float eb[B];
    float sb = 0.0f;
#pragma unroll
    for (int j = 0; j < B; ++j) { eb[j] = expf(ph[j] - mp); sb += eb[j]; }
    float bb[B];
#pragma unroll
    for (int j = 0; j < B; ++j) bb[j] = eb[j] / sb;

    // M[i][j] = exp(K),  K = (theta - C)/eps,  C = 0.5*trH*(delta^2/12)
    float M[B];
#pragma unroll
    for (int j = 0; j < B; ++j) {
        float denom = (float)((1 << bits[j]) - 1);
        float delta = 2.0f * wmax_i / denom;
        float C = 0.5f * trH_i * (delta * delta * (1.0f / 12.0f));
        M[j] = expf((theta[i * B + j] - C) * INV_EPS);
    }

    // packed column pairs
    v2f M2[3], u2[3], b2[3];
#pragma unroll
    for (int k = 0; k < 3; ++k) {
        M2[k].x = M[2 * k];     M2[k].y = M[2 * k + 1];
        b2[k].x = bb[2 * k];    b2[k].y = bb[2 * k + 1];
        u2[k].x = 1.0f;         u2[k].y = 1.0f;
    }

    float v = 0.0f;
#pragma unroll 1
    for (int it = 0; it < ITERS; ++it) {
        // v-update: v_i = a_i / sum_j M_ij u_j   (in-lane, packed fma tree)
        v2f acc = M2[0] * u2[0];
        acc = M2[1] * u2[1] + acc;
        acc = M2[2] * u2[2] + acc;
        float r = acc.x + acc.y;
        v = a_i * __builtin_amdgcn_rcpf(r);

        // u-update: u_j = b_j / sum_i M_ij v_i   (butterfly column sums)
        v2f vv; vv.x = v; vv.y = v;
#pragma unroll
        for (int k = 0; k < 3; ++k) {
            v2f w = M2[k] * vv;
            w = bfly_dpp<0xB1>(w);
            w = bfly_dpp<0x4E>(w);
            w = bfly_dpp<0x141>(w);
            w = bfly_dpp<0x140>(w);
            w = bfly_swap16(w);
            w = bfly_swap32(w);
            v2f uu;
            uu.x = b2[k].x * __builtin_amdgcn_rcpf(w.x);
            uu.y = b2[k].y * __builtin_amdgcn_rcpf(w.y);
            u2[k] = uu;
        }
    }

    // epilogue: P_ij = v_i * M_ij * u_j, normalized by global sum
    float p[B];
    float loc = 0.0f;
#pragma unroll
    for (int k = 0; k < 3; ++k) {
        v2f pp = (M2[k] * u2[k]);
        p[2 * k]     = pp.x * v;
        p[2 * k + 1] = pp.y * v;
        loc += p[2 * k] + p[2 * k + 1];
    }
    float tot = wave_allsum64(loc) + 1e-40f;
    float inv = __builtin_amdgcn_rcpf(tot);
#pragma unroll
    for (int j = 0; j < B; ++j) out[i * B + j] = p[j] * inv;
}

extern "C" void kernel_launch(void* const* d_in, const int* in_sizes, int n_in,
                              void* d_out, int out_size, void* d_ws, size_t ws_size,
                              hipStream_t stream) {
    const float* trH   = (const float*)d_in[0];
    const float* wmaxp = (const float*)d_in[1];
    const float* a     = (const float*)d_in[2];
    const float* theta = (const float*)d_in[3];
    const float* phi   = (const float*)d_in[4];
    const int*   bits  = (const int*)d_in[5];
    float* out = (float*)d_out;

    hipLaunchKernelGGL(dynot_sinkhorn_kernel, dim3(1), dim3(64), 0, stream,
                       trH, wmaxp, a, theta, phi, bits, out);
}

// Round 3
// 17.798 us; speedup vs baseline: 5.8082x; 3.5425x over previous
//
#include <hip/hip_runtime.h>
#include <math.h>

// DynOT: 200-iter Sinkhorn on 64x6, linear domain, one wave, lane i = row i.
//   v = a ./ (Mhat r),  r = rcp(Mtil^T v)
// where Mtil = M*diag(b), Mhat = M*diag(b^2), r_j = 1/(b_j S_j) so u_j = b_j^2 r_j.
// Column sums via DPP butterfly + gfx950 permlane swaps. No exp/log in loop.
// Early exit on EXACT period-<=2 cycle of the f32 map: bit-identical to 200 iters.

constexpr int B = 6;
constexpr int ITERS = 200;
constexpr float INV_EPS = 50.0f; // 1 / 0.02

typedef float v2f __attribute__((ext_vector_type(2)));

template <int CTRL>
__device__ __forceinline__ float dpp_mov(float v) {
    return __builtin_bit_cast(float,
        __builtin_amdgcn_update_dpp(0, __builtin_bit_cast(int, v), CTRL, 0xF, 0xF, true));
}

// x += shuffle(x); old=0 + bound_ctrl lets GCNDPPCombine fuse into v_add_f32_dpp.
// 0xB1 quad_perm xor1, 0x4E quad_perm xor2, 0x141 row_half_mirror (xor7 after
// quad-uniform == xor4), 0x140 row_mirror (xor15 after 8-uniform == xor8).
template <int CTRL>
__device__ __forceinline__ v2f bfly_dpp(v2f x) {
    v2f y;
    y.x = dpp_mov<CTRL>(x.x);
    y.y = dpp_mov<CTRL>(x.y);
    return x + y;
}

// xor16 / xor32 exchange via gfx950 permlane swaps; s_nop 1 covers the
// VALU-write -> permlane-read hazard (asm body is opaque to the scheduler).
__device__ __forceinline__ v2f bfly_swap16(v2f x) {
    float a0 = x.x, b0 = x.x, a1 = x.y, b1 = x.y;
    asm volatile("s_nop 1\n\t"
                 "v_permlane16_swap_b32 %0, %1\n\t"
                 "v_permlane16_swap_b32 %2, %3"
                 : "+v"(a0), "+v"(b0), "+v"(a1), "+v"(b1));
    v2f s, t;
    s.x = a0; s.y = a1;
    t.x = b0; t.y = b1;
    return s + t;
}
__device__ __forceinline__ v2f bfly_swap32(v2f x) {
    float a0 = x.x, b0 = x.x, a1 = x.y, b1 = x.y;
    asm volatile("s_nop 1\n\t"
                 "v_permlane32_swap_b32 %0, %1\n\t"
                 "v_permlane32_swap_b32 %2, %3"
                 : "+v"(a0), "+v"(b0), "+v"(a1), "+v"(b1));
    v2f s, t;
    s.x = a0; s.y = a1;
    t.x = b0; t.y = b1;
    return s + t;
}

__device__ __forceinline__ float wave_allsum64(float v) {
    v += dpp_mov<0xB1>(v);
    v += dpp_mov<0x4E>(v);
    v += dpp_mov<0x141>(v);
    v += dpp_mov<0x140>(v);
    {
        float a = v, b = v;
        asm volatile("s_nop 1\n\tv_permlane16_swap_b32 %0, %1" : "+v"(a), "+v"(b));
        v = a + b;
    }
    {
        float a = v, b = v;
        asm volatile("s_nop 1\n\tv_permlane32_swap_b32 %0, %1" : "+v"(a), "+v"(b));
        v = a + b;
    }
    return v;
}

__global__ __launch_bounds__(64) void dynot_sinkhorn_kernel(
    const float* __restrict__ trH, const float* __restrict__ wmax,
    const float* __restrict__ a, const float* __restrict__ theta,
    const float* __restrict__ phi, const int* __restrict__ bits,
    float* __restrict__ out)
{
    const int i = threadIdx.x; // row index, one wave of 64

    const float trH_i = trH[i];
    const float wmax_i = wmax[i];
    const float a_i = a[i];

    // b = softmax(phi), linear domain (uniform across lanes)
    float ph[B];
#pragma unroll
    for (int j = 0; j < B; ++j) ph[j] = phi[j];
    float mp = fmaxf(fmaxf(fmaxf(ph[0], ph[1]), fmaxf(ph[2], ph[3])), fmaxf(ph[4], ph[5]));
    float eb[B];
    float sb = 0.0f;
#pragma unroll
    for (int j = 0; j < B; ++j) { eb[j] = expf(ph[j] - mp); sb += eb[j]; }
    float bb[B];
#pragma unroll
    for (int j = 0; j < B; ++j) bb[j] = eb[j] / sb;

    // M[i][j] = exp((theta - C)/eps), C = 0.5*trH*(delta^2/12)
    // Mtil = M*b (column sums), Mhat = M*b^2 (row dot + epilogue)
    float Mt[B], Mh[B];
#pragma unroll
    for (int j = 0; j < B; ++j) {
        float denom = (float)((1 << bits[j]) - 1);
        float delta = 2.0f * wmax_i / denom;
        float C = 0.5f * trH_i * (delta * delta * (1.0f / 12.0f));
        float M = expf((theta[i * B + j] - C) * INV_EPS);
        Mt[j] = M * bb[j];
        Mh[j] = Mt[j] * bb[j];
    }

    v2f Mt2[3], Mh2[3], r2[3];
#pragma unroll
    for (int k = 0; k < 3; ++k) {
        Mt2[k].x = Mt[2 * k]; Mt2[k].y = Mt[2 * k + 1];
        Mh2[k].x = Mh[2 * k]; Mh2[k].y = Mh[2 * k + 1];
        // init u = 1  =>  r_j = 1/b_j^2
        r2[k].x = 1.0f / (bb[2 * k] * bb[2 * k]);
        r2[k].y = 1.0f / (bb[2 * k + 1] * bb[2 * k + 1]);
    }

    float v = 0.0f;

    auto body = [&]() {
        // v_i = a_i / sum_j Mhat_ij r_j   (2-level tree)
        v2f q0 = Mh2[0] * r2[0];
        v2f q1 = Mh2[1] * r2[1];
        v2f q2 = Mh2[2] * r2[2] + q0;
        v2f s2 = q2 + q1;
        float s = s2.x + s2.y;
        v = a_i * __builtin_amdgcn_rcpf(s);

        // r_j = rcp( sum_i Mtil_ij v_i )   (butterfly column sums)
        v2f vv; vv.x = v; vv.y = v;
#pragma unroll
        for (int k = 0; k < 3; ++k) {
            v2f w = Mt2[k] * vv;
            w = bfly_dpp<0xB1>(w);
            w = bfly_dpp<0x4E>(w);
            w = bfly_dpp<0x141>(w);
            w = bfly_dpp<0x140>(w);
            w = bfly_swap16(w);
            w = bfly_swap32(w);
            r2[k].x = __builtin_amdgcn_rcpf(w.x);
            r2[k].y = __builtin_amdgcn_rcpf(w.y);
        }
    };

    // Exact-cycle early exit: the f32 map is deterministic, so if v (all lanes)
    // repeats with period <=2 at even iteration k, state(200) == state(k) exactly.
    float vchk = __builtin_bit_cast(float, 0x7FC00001u); // never equals a finite v
#pragma unroll 1
    for (int it = 0; it < ITERS; it += 2) {
        body();
        body();
        unsigned d = __float_as_uint(v) ^ __float_as_uint(vchk);
        if (__all(d == 0)) break;
        vchk = v;
    }

    // epilogue: P_ij = v_i M_ij u_j = v_i Mhat_ij r_j, normalized by global sum
    float p[B];
    float loc = 0.0f;
#pragma unroll
    for (int k = 0; k < 3; ++k) {
        v2f pp = Mh2[k] * r2[k];
        p[2 * k]     = pp.x * v;
        p[2 * k + 1] = pp.y * v;
        loc += p[2 * k] + p[2 * k + 1];
    }
    float tot = wave_allsum64(loc) + 1e-40f;
    float inv = __builtin_amdgcn_rcpf(tot);
#pragma unroll
    for (int j = 0; j < B; ++j) out[i * B + j] = p[j] * inv;
}

extern "C" void kernel_launch(void* const* d_in, const int* in_sizes, int n_in,
                              void* d_out, int out_size, void* d_ws, size_t ws_size,
                              hipStream_t stream) {
    const float* trH   = (const float*)d_in[0];
    const float* wmaxp = (const float*)d_in[1];
    const float* a     = (const float*)d_in[2];
    const float* theta = (const float*)d_in[3];
    const float* phi   = (const float*)d_in[4];
    const int*   bits  = (const int*)d_in[5];
    float* out = (float*)d_out;

    hipLaunchKernelGGL(dynot_sinkhorn_kernel, dim3(1), dim3(64), 0, stream,
                       trH, wmaxp, a, theta, phi, bits, out);
}

// Round 4
// 10.335 us; speedup vs baseline: 10.0026x; 1.7222x over previous
//
#include <hip/hip_runtime.h>
#include <math.h>

// DynOT: Sinkhorn on 64x6, linear domain, one wave, lane i = row i.
// t-space iteration:  t = rcp(Mh r),  w = Mta^T t,  r = rcp(w)
// where Mh = M*diag(b^2), Mta = diag(a)*M*diag(b); v = a.*t, u = b^2 .* r.
// Column sums via DPP butterfly + gfx950 permlane swaps. No exp/log in loop.
// Exit: approx fixed point (|dt| <= 2^-19 t, all lanes) or exact period-2.

constexpr int B = 6;
constexpr int ITERS = 200;
constexpr float INV_EPS = 50.0f;        // 1 / 0.02
constexpr float EXIT_TOL = 1.9073486e-06f; // 2^-19

typedef float v2f __attribute__((ext_vector_type(2)));

template <int CTRL>
__device__ __forceinline__ float dpp_mov(float v) {
    return __builtin_bit_cast(float,
        __builtin_amdgcn_update_dpp(0, __builtin_bit_cast(int, v), CTRL, 0xF, 0xF, true));
}

// x += shuffle(x); old=0 + bound_ctrl lets GCNDPPCombine fuse into v_add_f32_dpp.
template <int CTRL>
__device__ __forceinline__ v2f bfly_dpp(v2f x) {
    v2f y;
    y.x = dpp_mov<CTRL>(x.x);
    y.y = dpp_mov<CTRL>(x.y);
    return x + y;
}

// xor16 / xor32 exchange via gfx950 permlane swaps; s_nop 1 covers the
// VALU-write -> permlane-read hazard (asm body is opaque to the scheduler).
__device__ __forceinline__ v2f bfly_swap16(v2f x) {
    float a0 = x.x, b0 = x.x, a1 = x.y, b1 = x.y;
    asm volatile("s_nop 1\n\t"
                 "v_permlane16_swap_b32 %0, %1\n\t"
                 "v_permlane16_swap_b32 %2, %3"
                 : "+v"(a0), "+v"(b0), "+v"(a1), "+v"(b1));
    v2f s, t;
    s.x = a0; s.y = a1;
    t.x = b0; t.y = b1;
    return s + t;
}
__device__ __forceinline__ v2f bfly_swap32(v2f x) {
    float a0 = x.x, b0 = x.x, a1 = x.y, b1 = x.y;
    asm volatile("s_nop 1\n\t"
                 "v_permlane32_swap_b32 %0, %1\n\t"
                 "v_permlane32_swap_b32 %2, %3"
                 : "+v"(a0), "+v"(b0), "+v"(a1), "+v"(b1));
    v2f s, t;
    s.x = a0; s.y = a1;
    t.x = b0; t.y = b1;
    return s + t;
}

__device__ __forceinline__ float wave_allsum64(float v) {
    v += dpp_mov<0xB1>(v);
    v += dpp_mov<0x4E>(v);
    v += dpp_mov<0x141>(v);
    v += dpp_mov<0x140>(v);
    {
        float a = v, b = v;
        asm volatile("s_nop 1\n\tv_permlane16_swap_b32 %0, %1" : "+v"(a), "+v"(b));
        v = a + b;
    }
    {
        float a = v, b = v;
        asm volatile("s_nop 1\n\tv_permlane32_swap_b32 %0, %1" : "+v"(a), "+v"(b));
        v = a + b;
    }
    return v;
}

__global__ __launch_bounds__(64) void dynot_sinkhorn_kernel(
    const float* __restrict__ trH, const float* __restrict__ wmax,
    const float* __restrict__ a, const float* __restrict__ theta,
    const float* __restrict__ phi, const int* __restrict__ bits,
    float* __restrict__ out)
{
    const int i = threadIdx.x; // row index, one wave of 64

    const float trH_i = trH[i];
    const float wmax_i = wmax[i];
    const float a_i = a[i];

    // b = softmax(phi), linear domain (uniform across lanes)
    float ph[B];
#pragma unroll
    for (int j = 0; j < B; ++j) ph[j] = phi[j];
    float mp = fmaxf(fmaxf(fmaxf(ph[0], ph[1]), fmaxf(ph[2], ph[3])), fmaxf(ph[4], ph[5]));
    float eb[B];
    float sb = 0.0f;
#pragma unroll
    for (int j = 0; j < B; ++j) { eb[j] = __expf(ph[j] - mp); sb += eb[j]; }
    float isb = 1.0f / sb;
    float bb[B];
#pragma unroll
    for (int j = 0; j < B; ++j) bb[j] = eb[j] * isb;

    // M[i][j] = exp((theta - C)/eps), C = 0.5*trH*(delta^2/12)
    // Mta = a*M*b (column-sum side), Mh = M*b^2 (row-dot side + epilogue)
    float Mta[B], Mh[B];
#pragma unroll
    for (int j = 0; j < B; ++j) {
        float denom = (float)((1 << bits[j]) - 1);
        float delta = 2.0f * wmax_i / denom;
        float C = 0.5f * trH_i * (delta * delta * (1.0f / 12.0f));
        float M = __expf((theta[i * B + j] - C) * INV_EPS);
        float Mb = M * bb[j];
        Mta[j] = Mb * a_i;
        Mh[j]  = Mb * bb[j];
    }

    v2f Mta2[3], Mh2[3], r2[3];
#pragma unroll
    for (int k = 0; k < 3; ++k) {
        Mta2[k].x = Mta[2 * k]; Mta2[k].y = Mta[2 * k + 1];
        Mh2[k].x  = Mh[2 * k];  Mh2[k].y  = Mh[2 * k + 1];
        // init u = 1  =>  r_j = 1/b_j^2
        r2[k].x = 1.0f / (bb[2 * k] * bb[2 * k]);
        r2[k].y = 1.0f / (bb[2 * k + 1] * bb[2 * k + 1]);
    }

    float t = 0.0f;
    float t_p1 = __builtin_bit_cast(float, 0x7FC00001u); // t at iter-1 (never matches)
    float t_p2 = __builtin_bit_cast(float, 0x7FC00003u); // t at iter-2

#pragma unroll 1
    for (int it = 0; it < ITERS; ++it) {
        // t_i = rcp( sum_j Mh_ij r_j )
        v2f q0 = Mh2[0] * r2[0];
        v2f q1 = Mh2[1] * r2[1];
        v2f q2 = Mh2[2] * r2[2];
        v2f s2 = (q0 + q1) + q2;
        float s = s2.x + s2.y;
        t = __builtin_amdgcn_rcpf(s);

        // r_j = rcp( sum_i Mta_ij t_i )   (butterfly column sums)
        v2f tt; tt.x = t; tt.y = t;
#pragma unroll
        for (int k = 0; k < 3; ++k) {
            v2f w = Mta2[k] * tt;
            w = bfly_dpp<0xB1>(w);
            w = bfly_dpp<0x4E>(w);
            w = bfly_dpp<0x141>(w);
            w = bfly_dpp<0x140>(w);
            w = bfly_swap16(w);
            w = bfly_swap32(w);
            r2[k].x = __builtin_amdgcn_rcpf(w.x);
            r2[k].y = __builtin_amdgcn_rcpf(w.y);
        }

        // Exit: approx fixed point (consecutive t within 2^-19 rel, all lanes),
        // or exact bitwise period-2 cycle (backstop; phase error ~1 ulp).
        float d1 = fabsf(t - t_p1);
        bool conv = (d1 <= t * EXIT_TOL);
        bool cyc = (__float_as_uint(t) == __float_as_uint(t_p2));
        if (__all(conv || cyc)) break;
        t_p2 = t_p1;
        t_p1 = t;
    }

    // epilogue: v_i = a_i t_i; P_ij = v_i Mh_ij r_j, normalized by global sum
    float v = a_i * t;
    float p[B];
    float loc = 0.0f;
#pragma unroll
    for (int k = 0; k < 3; ++k) {
        v2f pp = Mh2[k] * r2[k];
        p[2 * k]     = pp.x * v;
        p[2 * k + 1] = pp.y * v;
        loc += p[2 * k] + p[2 * k + 1];
    }
    float tot = wave_allsum64(loc) + 1e-40f;
    float inv = __builtin_amdgcn_rcpf(tot);
#pragma unroll
    for (int j = 0; j < B; ++j) out[i * B + j] = p[j] * inv;
}

extern "C" void kernel_launch(void* const* d_in, const int* in_sizes, int n_in,
                              void* d_out, int out_size, void* d_ws, size_t ws_size,
                              hipStream_t stream) {
    const float* trH   = (const float*)d_in[0];
    const float* wmaxp = (const float*)d_in[1];
    const float* a     = (const float*)d_in[2];
    const float* theta = (const float*)d_in[3];
    const float* phi   = (const float*)d_in[4];
    const int*   bits  = (const int*)d_in[5];
    float* out = (float*)d_out;

    hipLaunchKernelGGL(dynot_sinkhorn_kernel, dim3(1), dim3(64), 0, stream,
                       trH, wmaxp, a, theta, phi, bits, out);
}